// Round 2
// baseline (3194.000 us; speedup 1.0000x reference)
//
#include <hip/hip_runtime.h>

#define NN 100000
#define NE 1600000
#define HID 64
#define MSG_IN 156   // 2*64 + 2*6 + 16
#define W1E_OFF 140  // rows: [0:64) h_src, [64:128) h_dst, [128:134) sc_src, [134:140) sc_dst, [140:156) ef

__device__ __forceinline__ void mm4x4(float (&acc)[4][4], const float4 a, const float4 b) {
    acc[0][0] = fmaf(a.x, b.x, acc[0][0]);
    acc[0][1] = fmaf(a.x, b.y, acc[0][1]);
    acc[0][2] = fmaf(a.x, b.z, acc[0][2]);
    acc[0][3] = fmaf(a.x, b.w, acc[0][3]);
    acc[1][0] = fmaf(a.y, b.x, acc[1][0]);
    acc[1][1] = fmaf(a.y, b.y, acc[1][1]);
    acc[1][2] = fmaf(a.y, b.z, acc[1][2]);
    acc[1][3] = fmaf(a.y, b.w, acc[1][3]);
    acc[2][0] = fmaf(a.z, b.x, acc[2][0]);
    acc[2][1] = fmaf(a.z, b.y, acc[2][1]);
    acc[2][2] = fmaf(a.z, b.z, acc[2][2]);
    acc[2][3] = fmaf(a.z, b.w, acc[2][3]);
    acc[3][0] = fmaf(a.w, b.x, acc[3][0]);
    acc[3][1] = fmaf(a.w, b.y, acc[3][1]);
    acc[3][2] = fmaf(a.w, b.z, acc[3][2]);
    acc[3][3] = fmaf(a.w, b.w, acc[3][3]);
}

// h = x @ lin_w + lin_b   (tile: 64 nodes x 64 cols)
__global__ __launch_bounds__(256) void k_init(
    const float* __restrict__ x, const float* __restrict__ w,
    const float* __restrict__ b, float* __restrict__ h, int n)
{
    __shared__ __align__(16) float At[64][68];
    __shared__ __align__(16) float B[64][64];
    const int tid = threadIdx.x;
    const int m0 = blockIdx.x * 64;
    for (int i = tid; i < 1024; i += 256)
        ((float4*)B)[i] = ((const float4*)w)[i];
    for (int i = tid; i < 1024; i += 256) {
        int m = i >> 4, f4 = i & 15, k4 = f4 * 4;
        int node = m0 + m;
        float4 v = make_float4(0.f, 0.f, 0.f, 0.f);
        if (node < n) v = ((const float4*)x)[node * 16 + f4];
        At[k4 + 0][m] = v.x; At[k4 + 1][m] = v.y; At[k4 + 2][m] = v.z; At[k4 + 3][m] = v.w;
    }
    __syncthreads();
    const int ty = tid >> 4, tx = tid & 15;
    float acc[4][4];
    {
        float4 bb = ((const float4*)b)[tx];
        #pragma unroll
        for (int r = 0; r < 4; ++r) { acc[r][0] = bb.x; acc[r][1] = bb.y; acc[r][2] = bb.z; acc[r][3] = bb.w; }
    }
    #pragma unroll 8
    for (int k = 0; k < 64; ++k) {
        float4 a = *(const float4*)&At[k][ty * 4];
        float4 bv = *(const float4*)&B[k][tx * 4];
        mm4x4(acc, a, bv);
    }
    #pragma unroll
    for (int r = 0; r < 4; ++r) {
        int node = m0 + ty * 4 + r;
        if (node < n)
            ((float4*)h)[node * 16 + tx] = make_float4(acc[r][0], acc[r][1], acc[r][2], acc[r][3]);
    }
}

// p = h@W1a + sc@W1c ; q = h@W1b + sc@W1d + b1
__global__ __launch_bounds__(256) void k_pq(
    const float* __restrict__ h, const int* __restrict__ nsc,
    const float* __restrict__ w1, const float* __restrict__ b1,
    float* __restrict__ p, float* __restrict__ q, int n)
{
    __shared__ __align__(16) float At[64][68];
    __shared__ __align__(16) float Bp[64][64];
    __shared__ __align__(16) float Bq[64][64];
    __shared__ __align__(16) float Sct[6][68];
    __shared__ __align__(16) float Bc[6][64];
    __shared__ __align__(16) float Bd[6][64];
    const int tid = threadIdx.x;
    const int m0 = blockIdx.x * 64;
    for (int i = tid; i < 1024; i += 256) {
        ((float4*)Bp)[i] = ((const float4*)w1)[i];
        ((float4*)Bq)[i] = ((const float4*)(w1 + 64 * 64))[i];
    }
    if (tid < 96) {
        ((float4*)Bc)[tid] = ((const float4*)(w1 + 128 * 64))[tid];
        ((float4*)Bd)[tid] = ((const float4*)(w1 + 134 * 64))[tid];
    }
    for (int i = tid; i < 1024; i += 256) {
        int m = i >> 4, f4 = i & 15, k4 = f4 * 4;
        int node = m0 + m;
        float4 v = make_float4(0.f, 0.f, 0.f, 0.f);
        if (node < n) v = ((const float4*)h)[node * 16 + f4];
        At[k4 + 0][m] = v.x; At[k4 + 1][m] = v.y; At[k4 + 2][m] = v.z; At[k4 + 3][m] = v.w;
    }
    // 384 elements with 256 threads: MUST grid-stride (R0 bug: rows k=4,5 never loaded)
    for (int i = tid; i < 384; i += 256) {
        int m = i & 63, k = i >> 6;
        int node = m0 + m;
        float v = 0.f;
        if (node < n) v = (float)nsc[node * 6 + k];
        Sct[k][m] = v;
    }
    __syncthreads();
    const int ty = tid >> 4, tx = tid & 15;
    float ap[4][4], aq[4][4];
    {
        float4 bb = ((const float4*)b1)[tx];
        #pragma unroll
        for (int r = 0; r < 4; ++r) {
            ap[r][0] = 0.f; ap[r][1] = 0.f; ap[r][2] = 0.f; ap[r][3] = 0.f;
            aq[r][0] = bb.x; aq[r][1] = bb.y; aq[r][2] = bb.z; aq[r][3] = bb.w;
        }
    }
    #pragma unroll 8
    for (int k = 0; k < 64; ++k) {
        float4 a  = *(const float4*)&At[k][ty * 4];
        float4 bp = *(const float4*)&Bp[k][tx * 4];
        float4 bq = *(const float4*)&Bq[k][tx * 4];
        mm4x4(ap, a, bp);
        mm4x4(aq, a, bq);
    }
    #pragma unroll
    for (int k = 0; k < 6; ++k) {
        float4 a  = *(const float4*)&Sct[k][ty * 4];
        float4 bc = *(const float4*)&Bc[k][tx * 4];
        float4 bd = *(const float4*)&Bd[k][tx * 4];
        mm4x4(ap, a, bc);
        mm4x4(aq, a, bd);
    }
    #pragma unroll
    for (int r = 0; r < 4; ++r) {
        int node = m0 + ty * 4 + r;
        if (node < n) {
            ((float4*)p)[node * 16 + tx] = make_float4(ap[r][0], ap[r][1], ap[r][2], ap[r][3]);
            ((float4*)q)[node * 16 + tx] = make_float4(aq[r][0], aq[r][1], aq[r][2], aq[r][3]);
        }
    }
}

// per 64-edge tile: hidden = relu(p[src]+q[dst]+ef@W1e); out = hidden@W2 + b2; atomic scatter to upd[dst]
__global__ __launch_bounds__(256) void k_edge(
    const int* __restrict__ el, const float* __restrict__ ef,
    const float* __restrict__ ew,
    const float* __restrict__ p, const float* __restrict__ q,
    const float* __restrict__ w1e, const float* __restrict__ w2,
    const float* __restrict__ b2,
    float* __restrict__ upd, int n_edges)
{
    __shared__ __align__(16) float Et[16][68];
    __shared__ __align__(16) float W1e[16][64];
    __shared__ __align__(16) float Ht[64][68];
    __shared__ __align__(16) float W2[64][64];
    __shared__ int Ssrc[64];
    __shared__ int Sdst[64];
    __shared__ float Sew[64];
    const int tid = threadIdx.x;
    const int e0 = blockIdx.x * 64;
    if (tid < 64) {
        int e = e0 + tid;
        int2 sd = make_int2(0, 0);
        float w = 0.f;
        if (e < n_edges) { sd = ((const int2*)el)[e]; w = ew[e]; }
        Ssrc[tid] = sd.x; Sdst[tid] = sd.y; Sew[tid] = w;
    }
    ((float4*)W1e)[tid] = ((const float4*)w1e)[tid];
    for (int i = tid; i < 1024; i += 256)
        ((float4*)W2)[i] = ((const float4*)w2)[i];
    {
        int e = tid >> 2, f4 = tid & 3, k4 = f4 * 4;
        int ge = e0 + e;
        float4 v = make_float4(0.f, 0.f, 0.f, 0.f);
        if (ge < n_edges) v = ((const float4*)ef)[ge * 4 + f4];
        Et[k4 + 0][e] = v.x; Et[k4 + 1][e] = v.y; Et[k4 + 2][e] = v.z; Et[k4 + 3][e] = v.w;
    }
    __syncthreads();
    const int ty = tid >> 4, tx = tid & 15;
    float acc[4][4];
    #pragma unroll
    for (int r = 0; r < 4; ++r) {
        int s = Ssrc[ty * 4 + r], d = Sdst[ty * 4 + r];
        float4 pv = ((const float4*)p)[(size_t)s * 16 + tx];
        float4 qv = ((const float4*)q)[(size_t)d * 16 + tx];
        acc[r][0] = pv.x + qv.x; acc[r][1] = pv.y + qv.y;
        acc[r][2] = pv.z + qv.z; acc[r][3] = pv.w + qv.w;
    }
    #pragma unroll
    for (int k = 0; k < 16; ++k) {
        float4 a = *(const float4*)&Et[k][ty * 4];
        float4 b = *(const float4*)&W1e[k][tx * 4];
        mm4x4(acc, a, b);
    }
    #pragma unroll
    for (int r = 0; r < 4; ++r)
        #pragma unroll
        for (int c = 0; c < 4; ++c)
            Ht[tx * 4 + c][ty * 4 + r] = fmaxf(acc[r][c], 0.f);
    __syncthreads();
    float acc2[4][4];
    {
        float4 bb = ((const float4*)b2)[tx];
        #pragma unroll
        for (int r = 0; r < 4; ++r) { acc2[r][0] = bb.x; acc2[r][1] = bb.y; acc2[r][2] = bb.z; acc2[r][3] = bb.w; }
    }
    #pragma unroll 8
    for (int k = 0; k < 64; ++k) {
        float4 a = *(const float4*)&Ht[k][ty * 4];
        float4 b = *(const float4*)&W2[k][tx * 4];
        mm4x4(acc2, a, b);
    }
    #pragma unroll
    for (int r = 0; r < 4; ++r) {
        int le = ty * 4 + r;
        int ge = e0 + le;
        if (ge < n_edges) {
            int d = Sdst[le];
            float w = Sew[le];
            #pragma unroll
            for (int c = 0; c < 4; ++c)
                atomicAdd(&upd[(size_t)d * 64 + tx * 4 + c], acc2[r][c] * w);
        }
    }
}

// h = relu(relu([h,upd]@uw1 + ub1)@uw2 + ub2); optional fused graph segment-sum
__global__ __launch_bounds__(256) void k_update(
    float* __restrict__ h, const float* __restrict__ upd,
    const float* __restrict__ w1, const float* __restrict__ b1,
    const float* __restrict__ w2, const float* __restrict__ b2,
    int n, int write_out, float* __restrict__ out_graph,
    const int* __restrict__ n2g)
{
    __shared__ __align__(16) float At[64][68];
    __shared__ __align__(16) float B1[128][64];
    const int tid = threadIdx.x;
    const int m0 = blockIdx.x * 64;
    const int ty = tid >> 4, tx = tid & 15;
    for (int i = tid; i < 2048; i += 256)
        ((float4*)B1)[i] = ((const float4*)w1)[i];
    for (int i = tid; i < 1024; i += 256) {
        int m = i >> 4, f4 = i & 15, k4 = f4 * 4;
        int node = m0 + m;
        float4 v = make_float4(0.f, 0.f, 0.f, 0.f);
        if (node < n) v = ((const float4*)h)[node * 16 + f4];
        At[k4 + 0][m] = v.x; At[k4 + 1][m] = v.y; At[k4 + 2][m] = v.z; At[k4 + 3][m] = v.w;
    }
    __syncthreads();
    float acc[4][4];
    {
        float4 bb = ((const float4*)b1)[tx];
        #pragma unroll
        for (int r = 0; r < 4; ++r) { acc[r][0] = bb.x; acc[r][1] = bb.y; acc[r][2] = bb.z; acc[r][3] = bb.w; }
    }
    #pragma unroll 8
    for (int k = 0; k < 64; ++k) {
        float4 a = *(const float4*)&At[k][ty * 4];
        float4 b = *(const float4*)&B1[k][tx * 4];
        mm4x4(acc, a, b);
    }
    __syncthreads();
    for (int i = tid; i < 1024; i += 256) {
        int m = i >> 4, f4 = i & 15, k4 = f4 * 4;
        int node = m0 + m;
        float4 v = make_float4(0.f, 0.f, 0.f, 0.f);
        if (node < n) v = ((const float4*)upd)[node * 16 + f4];
        At[k4 + 0][m] = v.x; At[k4 + 1][m] = v.y; At[k4 + 2][m] = v.z; At[k4 + 3][m] = v.w;
    }
    __syncthreads();
    #pragma unroll 8
    for (int k = 0; k < 64; ++k) {
        float4 a = *(const float4*)&At[k][ty * 4];
        float4 b = *(const float4*)&B1[64 + k][tx * 4];
        mm4x4(acc, a, b);
    }
    __syncthreads();
    // hidden (relu) -> At transposed; w2 -> B1 front
    #pragma unroll
    for (int r = 0; r < 4; ++r)
        #pragma unroll
        for (int c = 0; c < 4; ++c)
            At[tx * 4 + c][ty * 4 + r] = fmaxf(acc[r][c], 0.f);
    for (int i = tid; i < 1024; i += 256)
        ((float4*)B1)[i] = ((const float4*)w2)[i];
    __syncthreads();
    float acc2[4][4];
    {
        float4 bb = ((const float4*)b2)[tx];
        #pragma unroll
        for (int r = 0; r < 4; ++r) { acc2[r][0] = bb.x; acc2[r][1] = bb.y; acc2[r][2] = bb.z; acc2[r][3] = bb.w; }
    }
    #pragma unroll 8
    for (int k = 0; k < 64; ++k) {
        float4 a = *(const float4*)&At[k][ty * 4];
        float4 b = *(const float4*)&B1[k][tx * 4];
        mm4x4(acc2, a, b);
    }
    float hv[4][4];
    #pragma unroll
    for (int r = 0; r < 4; ++r)
        #pragma unroll
        for (int c = 0; c < 4; ++c)
            hv[r][c] = fmaxf(acc2[r][c], 0.f);
    #pragma unroll
    for (int r = 0; r < 4; ++r) {
        int node = m0 + ty * 4 + r;
        if (node < n)
            ((float4*)h)[node * 16 + tx] = make_float4(hv[r][0], hv[r][1], hv[r][2], hv[r][3]);
    }
    if (write_out) {
        int curg = -1;
        float s0 = 0.f, s1 = 0.f, s2 = 0.f, s3 = 0.f;
        #pragma unroll
        for (int r = 0; r < 4; ++r) {
            int node = m0 + ty * 4 + r;
            if (node < n) {
                int g = n2g[node];
                if (g != curg) {
                    if (curg >= 0) {
                        atomicAdd(&out_graph[curg * 64 + tx * 4 + 0], s0);
                        atomicAdd(&out_graph[curg * 64 + tx * 4 + 1], s1);
                        atomicAdd(&out_graph[curg * 64 + tx * 4 + 2], s2);
                        atomicAdd(&out_graph[curg * 64 + tx * 4 + 3], s3);
                    }
                    curg = g; s0 = hv[r][0]; s1 = hv[r][1]; s2 = hv[r][2]; s3 = hv[r][3];
                } else {
                    s0 += hv[r][0]; s1 += hv[r][1]; s2 += hv[r][2]; s3 += hv[r][3];
                }
            }
        }
        if (curg >= 0) {
            atomicAdd(&out_graph[curg * 64 + tx * 4 + 0], s0);
            atomicAdd(&out_graph[curg * 64 + tx * 4 + 1], s1);
            atomicAdd(&out_graph[curg * 64 + tx * 4 + 2], s2);
            atomicAdd(&out_graph[curg * 64 + tx * 4 + 3], s3);
        }
    }
}

extern "C" void kernel_launch(void* const* d_in, const int* in_sizes, int n_in,
                              void* d_out, int out_size, void* d_ws, size_t ws_size,
                              hipStream_t stream)
{
    const float* x       = (const float*)d_in[0];
    const int*   el      = (const int*)d_in[1];
    const int*   nsc     = (const int*)d_in[2];
    const float* ef      = (const float*)d_in[3];
    const float* ew      = (const float*)d_in[4];
    const int*   n2g     = (const int*)d_in[5];
    const float* lin_w   = (const float*)d_in[7];
    const float* lin_b   = (const float*)d_in[8];
    const float* msg_w1  = (const float*)d_in[9];
    const float* msg_b1  = (const float*)d_in[10];
    const float* msg_w2  = (const float*)d_in[11];
    const float* msg_b2  = (const float*)d_in[12];
    const float* upd_w1  = (const float*)d_in[13];
    const float* upd_b1  = (const float*)d_in[14];
    const float* upd_w2  = (const float*)d_in[15];
    const float* upd_b2  = (const float*)d_in[16];

    float* out_graph = (float*)d_out;              // 128*64
    float* h   = (float*)d_out + 128 * 64;         // node_feature region doubles as h
    float* p   = (float*)d_ws;
    float* q   = p + (size_t)NN * HID;
    float* upd = q + (size_t)NN * HID;

    const int nblk_n = (NN + 63) / 64;
    const int nblk_e = (NE + 63) / 64;

    hipMemsetAsync(d_out, 0, 128 * 64 * sizeof(float), stream);
    k_init<<<nblk_n, 256, 0, stream>>>(x, lin_w, lin_b, h, NN);
    for (int l = 0; l < 2; ++l) {
        const float* w1 = msg_w1 + (size_t)l * MSG_IN * HID;
        k_pq<<<nblk_n, 256, 0, stream>>>(h, nsc, w1, msg_b1 + l * HID, p, q, NN);
        hipMemsetAsync(upd, 0, (size_t)NN * HID * sizeof(float), stream);
        k_edge<<<nblk_e, 256, 0, stream>>>(el, ef, ew, p, q,
                                           w1 + W1E_OFF * HID,
                                           msg_w2 + (size_t)l * HID * HID,
                                           msg_b2 + l * HID, upd, NE);
        k_update<<<nblk_n, 256, 0, stream>>>(h, upd,
                                             upd_w1 + (size_t)l * 2 * HID * HID,
                                             upd_b1 + l * HID,
                                             upd_w2 + (size_t)l * HID * HID,
                                             upd_b2 + l * HID,
                                             NN, (l == 1) ? 1 : 0, out_graph, n2g);
    }
}

// Round 4
// 1861.125 us; speedup vs baseline: 1.7162x; 1.7162x over previous
//
#include <hip/hip_runtime.h>

#define NN 100000
#define NE 1600000
#define HID 64
#define MSG_IN 156   // 2*64 + 2*6 + 16
#define W1E_OFF 140  // rows: [0:64) h_src, [64:128) h_dst, [128:134) sc_src, [134:140) sc_dst, [140:156) ef

__device__ __forceinline__ void mm4x4(float (&acc)[4][4], const float4 a, const float4 b) {
    acc[0][0] = fmaf(a.x, b.x, acc[0][0]);
    acc[0][1] = fmaf(a.x, b.y, acc[0][1]);
    acc[0][2] = fmaf(a.x, b.z, acc[0][2]);
    acc[0][3] = fmaf(a.x, b.w, acc[0][3]);
    acc[1][0] = fmaf(a.y, b.x, acc[1][0]);
    acc[1][1] = fmaf(a.y, b.y, acc[1][1]);
    acc[1][2] = fmaf(a.y, b.z, acc[1][2]);
    acc[1][3] = fmaf(a.y, b.w, acc[1][3]);
    acc[2][0] = fmaf(a.z, b.x, acc[2][0]);
    acc[2][1] = fmaf(a.z, b.y, acc[2][1]);
    acc[2][2] = fmaf(a.z, b.z, acc[2][2]);
    acc[2][3] = fmaf(a.z, b.w, acc[2][3]);
    acc[3][0] = fmaf(a.w, b.x, acc[3][0]);
    acc[3][1] = fmaf(a.w, b.y, acc[3][1]);
    acc[3][2] = fmaf(a.w, b.z, acc[3][2]);
    acc[3][3] = fmaf(a.w, b.w, acc[3][3]);
}

// ---------------- counting sort of edges by dst (tiered on ws_size) ----------------

__global__ __launch_bounds__(256) void k_hist(
    const int* __restrict__ el, int* __restrict__ counts, int n_edges)
{
    int e = blockIdx.x * 256 + threadIdx.x;
    if (e < n_edges) {
        int2 sd = ((const int2*)el)[e];
        atomicAdd(&counts[sd.y], 1);
    }
}

__global__ __launch_bounds__(256) void k_scan1(
    const int* __restrict__ counts, int* __restrict__ offs,
    int* __restrict__ blksum, int n)
{
    __shared__ int s[256];
    const int tid = threadIdx.x;
    int i = blockIdx.x * 256 + tid;
    int v = (i < n) ? counts[i] : 0;
    s[tid] = v;
    for (int off = 1; off < 256; off <<= 1) {
        __syncthreads();
        int t = (tid >= off) ? s[tid - off] : 0;
        __syncthreads();
        s[tid] += t;
    }
    __syncthreads();
    if (i < n) offs[i] = s[tid] - v;            // exclusive within block
    if (tid == 255) blksum[blockIdx.x] = s[255];
}

__global__ __launch_bounds__(512) void k_scan2(int* __restrict__ blksum, int nb)
{
    __shared__ int s[512];
    const int tid = threadIdx.x;
    int v = (tid < nb) ? blksum[tid] : 0;
    s[tid] = v;
    for (int off = 1; off < 512; off <<= 1) {
        __syncthreads();
        int t = (tid >= off) ? s[tid - off] : 0;
        __syncthreads();
        s[tid] += t;
    }
    __syncthreads();
    if (tid < nb) blksum[tid] = s[tid] - v;     // exclusive
}

__global__ __launch_bounds__(256) void k_scan3(
    int* __restrict__ offs, const int* __restrict__ blksum, int n)
{
    int i = blockIdx.x * 256 + threadIdx.x;
    if (i < n) offs[i] += blksum[blockIdx.x];
}

// scatter edges to dst-sorted positions; offs consumed as cursor; sd_s optional
__global__ __launch_bounds__(256) void k_permute(
    const int* __restrict__ el,
    int* __restrict__ cursor, int* __restrict__ perm,
    int2* __restrict__ sd_s, int n_edges)
{
    int e = blockIdx.x * 256 + threadIdx.x;
    if (e < n_edges) {
        int2 sd = ((const int2*)el)[e];
        int pos = atomicAdd(&cursor[sd.y], 1);
        perm[pos] = e;
        if (sd_s) sd_s[pos] = sd;
    }
}

// ---------------- dense per-tile GEMM kernels ----------------

// h = x @ lin_w + lin_b
__global__ __launch_bounds__(256) void k_init(
    const float* __restrict__ x, const float* __restrict__ w,
    const float* __restrict__ b, float* __restrict__ h, int n)
{
    __shared__ __align__(16) float At[64][68];
    __shared__ __align__(16) float B[64][64];
    const int tid = threadIdx.x;
    const int m0 = blockIdx.x * 64;
    for (int i = tid; i < 1024; i += 256)
        ((float4*)B)[i] = ((const float4*)w)[i];
    for (int i = tid; i < 1024; i += 256) {
        int m = i >> 4, f4 = i & 15, k4 = f4 * 4;
        int node = m0 + m;
        float4 v = make_float4(0.f, 0.f, 0.f, 0.f);
        if (node < n) v = ((const float4*)x)[node * 16 + f4];
        At[k4 + 0][m] = v.x; At[k4 + 1][m] = v.y; At[k4 + 2][m] = v.z; At[k4 + 3][m] = v.w;
    }
    __syncthreads();
    const int ty = tid >> 4, tx = tid & 15;
    float acc[4][4];
    {
        float4 bb = ((const float4*)b)[tx];
        #pragma unroll
        for (int r = 0; r < 4; ++r) { acc[r][0] = bb.x; acc[r][1] = bb.y; acc[r][2] = bb.z; acc[r][3] = bb.w; }
    }
    #pragma unroll 8
    for (int k = 0; k < 64; ++k) {
        float4 a = *(const float4*)&At[k][ty * 4];
        float4 bv = *(const float4*)&B[k][tx * 4];
        mm4x4(acc, a, bv);
    }
    #pragma unroll
    for (int r = 0; r < 4; ++r) {
        int node = m0 + ty * 4 + r;
        if (node < n)
            ((float4*)h)[node * 16 + tx] = make_float4(acc[r][0], acc[r][1], acc[r][2], acc[r][3]);
    }
}

// p = h@W1a + sc@W1c ; q = h@W1b + sc@W1d + b1
__global__ __launch_bounds__(256) void k_pq(
    const float* __restrict__ h, const int* __restrict__ nsc,
    const float* __restrict__ w1, const float* __restrict__ b1,
    float* __restrict__ p, float* __restrict__ q, int n)
{
    __shared__ __align__(16) float At[64][68];
    __shared__ __align__(16) float Bp[64][64];
    __shared__ __align__(16) float Bq[64][64];
    __shared__ __align__(16) float Sct[6][68];
    __shared__ __align__(16) float Bc[6][64];
    __shared__ __align__(16) float Bd[6][64];
    const int tid = threadIdx.x;
    const int m0 = blockIdx.x * 64;
    for (int i = tid; i < 1024; i += 256) {
        ((float4*)Bp)[i] = ((const float4*)w1)[i];
        ((float4*)Bq)[i] = ((const float4*)(w1 + 64 * 64))[i];
    }
    if (tid < 96) {
        ((float4*)Bc)[tid] = ((const float4*)(w1 + 128 * 64))[tid];
        ((float4*)Bd)[tid] = ((const float4*)(w1 + 134 * 64))[tid];
    }
    for (int i = tid; i < 1024; i += 256) {
        int m = i >> 4, f4 = i & 15, k4 = f4 * 4;
        int node = m0 + m;
        float4 v = make_float4(0.f, 0.f, 0.f, 0.f);
        if (node < n) v = ((const float4*)h)[node * 16 + f4];
        At[k4 + 0][m] = v.x; At[k4 + 1][m] = v.y; At[k4 + 2][m] = v.z; At[k4 + 3][m] = v.w;
    }
    for (int i = tid; i < 384; i += 256) {      // grid-stride: 384 elems, 256 threads
        int m = i & 63, k = i >> 6;
        int node = m0 + m;
        float v = 0.f;
        if (node < n) v = (float)nsc[node * 6 + k];
        Sct[k][m] = v;
    }
    __syncthreads();
    const int ty = tid >> 4, tx = tid & 15;
    float ap[4][4], aq[4][4];
    {
        float4 bb = ((const float4*)b1)[tx];
        #pragma unroll
        for (int r = 0; r < 4; ++r) {
            ap[r][0] = 0.f; ap[r][1] = 0.f; ap[r][2] = 0.f; ap[r][3] = 0.f;
            aq[r][0] = bb.x; aq[r][1] = bb.y; aq[r][2] = bb.z; aq[r][3] = bb.w;
        }
    }
    #pragma unroll 8
    for (int k = 0; k < 64; ++k) {
        float4 a  = *(const float4*)&At[k][ty * 4];
        float4 bp = *(const float4*)&Bp[k][tx * 4];
        float4 bq = *(const float4*)&Bq[k][tx * 4];
        mm4x4(ap, a, bp);
        mm4x4(aq, a, bq);
    }
    #pragma unroll
    for (int k = 0; k < 6; ++k) {
        float4 a  = *(const float4*)&Sct[k][ty * 4];
        float4 bc = *(const float4*)&Bc[k][tx * 4];
        float4 bd = *(const float4*)&Bd[k][tx * 4];
        mm4x4(ap, a, bc);
        mm4x4(aq, a, bd);
    }
    #pragma unroll
    for (int r = 0; r < 4; ++r) {
        int node = m0 + ty * 4 + r;
        if (node < n) {
            ((float4*)p)[node * 16 + tx] = make_float4(ap[r][0], ap[r][1], ap[r][2], ap[r][3]);
            ((float4*)q)[node * 16 + tx] = make_float4(aq[r][0], aq[r][1], aq[r][2], aq[r][3]);
        }
    }
}

// edge tile (optionally dst-sorted): hidden = relu(p[src]+q[dst]+ef@W1e);
// out = hidden@W2+b2; run-length-reduced atomic scatter to upd[dst]
// sd_s: sorted (src,dst) or null; perm: sorted->orig edge map or null (identity)
__global__ __launch_bounds__(256) void k_edge(
    const int2* __restrict__ sd_s, const int* __restrict__ perm,
    const int2* __restrict__ el2, const float* __restrict__ ew,
    const float* __restrict__ ef,
    const float* __restrict__ p, const float* __restrict__ q,
    const float* __restrict__ w1e, const float* __restrict__ w2,
    const float* __restrict__ b2,
    float* __restrict__ upd, int n_edges)
{
    __shared__ __align__(16) float Et[16][68];
    __shared__ __align__(16) float W1e[16][64];
    __shared__ __align__(16) float Ht[64][68];
    __shared__ __align__(16) float W2[64][64];
    __shared__ int Ssrc[64];
    __shared__ int Sdst[64];
    __shared__ float Sew[64];
    const int tid = threadIdx.x;
    const int e0 = blockIdx.x * 64;
    if (tid < 64) {
        int e = e0 + tid;
        int s = 0, d = 0; float w = 0.f;
        if (e < n_edges) {
            int pe = perm ? perm[e] : e;
            int2 sd = sd_s ? sd_s[e] : el2[pe];
            s = sd.x; d = sd.y; w = ew[pe];
        }
        Ssrc[tid] = s; Sdst[tid] = d; Sew[tid] = w;
    }
    ((float4*)W1e)[tid] = ((const float4*)w1e)[tid];
    for (int i = tid; i < 1024; i += 256)
        ((float4*)W2)[i] = ((const float4*)w2)[i];
    {
        int e = tid >> 2, f4 = tid & 3, k4 = f4 * 4;
        int ge = e0 + e;
        float4 v = make_float4(0.f, 0.f, 0.f, 0.f);
        if (ge < n_edges) {
            int pe = perm ? perm[ge] : ge;          // 4 lanes share one perm read
            v = ((const float4*)ef)[(size_t)pe * 4 + f4];
        }
        Et[k4 + 0][e] = v.x; Et[k4 + 1][e] = v.y; Et[k4 + 2][e] = v.z; Et[k4 + 3][e] = v.w;
    }
    __syncthreads();
    const int ty = tid >> 4, tx = tid & 15;
    float acc[4][4];
    #pragma unroll
    for (int r = 0; r < 4; ++r) {
        int s = Ssrc[ty * 4 + r], d = Sdst[ty * 4 + r];
        float4 pv = ((const float4*)p)[(size_t)s * 16 + tx];
        float4 qv = ((const float4*)q)[(size_t)d * 16 + tx];   // sorted: mostly cache hits
        acc[r][0] = pv.x + qv.x; acc[r][1] = pv.y + qv.y;
        acc[r][2] = pv.z + qv.z; acc[r][3] = pv.w + qv.w;
    }
    #pragma unroll
    for (int k = 0; k < 16; ++k) {
        float4 a = *(const float4*)&Et[k][ty * 4];
        float4 b = *(const float4*)&W1e[k][tx * 4];
        mm4x4(acc, a, b);
    }
    #pragma unroll
    for (int r = 0; r < 4; ++r)
        #pragma unroll
        for (int c = 0; c < 4; ++c)
            Ht[tx * 4 + c][ty * 4 + r] = fmaxf(acc[r][c], 0.f);
    __syncthreads();
    float acc2[4][4];
    {
        float4 bb = ((const float4*)b2)[tx];
        #pragma unroll
        for (int r = 0; r < 4; ++r) { acc2[r][0] = bb.x; acc2[r][1] = bb.y; acc2[r][2] = bb.z; acc2[r][3] = bb.w; }
    }
    #pragma unroll 8
    for (int k = 0; k < 64; ++k) {
        float4 a = *(const float4*)&Ht[k][ty * 4];
        float4 b = *(const float4*)&W2[k][tx * 4];
        mm4x4(acc2, a, b);
    }
    // run-length reduction over this thread's 4 consecutive (sorted) edges
    {
        int curd = -1;
        float s0 = 0.f, s1 = 0.f, s2 = 0.f, s3 = 0.f;
        #pragma unroll
        for (int r = 0; r < 4; ++r) {
            int le = ty * 4 + r;
            int ge = e0 + le;
            if (ge < n_edges) {
                int d = Sdst[le];
                float w = Sew[le];
                if (d != curd) {
                    if (curd >= 0) {
                        atomicAdd(&upd[(size_t)curd * 64 + tx * 4 + 0], s0);
                        atomicAdd(&upd[(size_t)curd * 64 + tx * 4 + 1], s1);
                        atomicAdd(&upd[(size_t)curd * 64 + tx * 4 + 2], s2);
                        atomicAdd(&upd[(size_t)curd * 64 + tx * 4 + 3], s3);
                    }
                    curd = d;
                    s0 = acc2[r][0] * w; s1 = acc2[r][1] * w;
                    s2 = acc2[r][2] * w; s3 = acc2[r][3] * w;
                } else {
                    s0 += acc2[r][0] * w; s1 += acc2[r][1] * w;
                    s2 += acc2[r][2] * w; s3 += acc2[r][3] * w;
                }
            }
        }
        if (curd >= 0) {
            atomicAdd(&upd[(size_t)curd * 64 + tx * 4 + 0], s0);
            atomicAdd(&upd[(size_t)curd * 64 + tx * 4 + 1], s1);
            atomicAdd(&upd[(size_t)curd * 64 + tx * 4 + 2], s2);
            atomicAdd(&upd[(size_t)curd * 64 + tx * 4 + 3], s3);
        }
    }
}

// h = relu(relu([h,upd]@uw1 + ub1)@uw2 + ub2); optional fused graph segment-sum
__global__ __launch_bounds__(256) void k_update(
    float* __restrict__ h, const float* __restrict__ upd,
    const float* __restrict__ w1, const float* __restrict__ b1,
    const float* __restrict__ w2, const float* __restrict__ b2,
    int n, int write_out, float* __restrict__ out_graph,
    const int* __restrict__ n2g)
{
    __shared__ __align__(16) float At[64][68];
    __shared__ __align__(16) float B1[128][64];
    const int tid = threadIdx.x;
    const int m0 = blockIdx.x * 64;
    const int ty = tid >> 4, tx = tid & 15;
    for (int i = tid; i < 2048; i += 256)
        ((float4*)B1)[i] = ((const float4*)w1)[i];
    for (int i = tid; i < 1024; i += 256) {
        int m = i >> 4, f4 = i & 15, k4 = f4 * 4;
        int node = m0 + m;
        float4 v = make_float4(0.f, 0.f, 0.f, 0.f);
        if (node < n) v = ((const float4*)h)[node * 16 + f4];
        At[k4 + 0][m] = v.x; At[k4 + 1][m] = v.y; At[k4 + 2][m] = v.z; At[k4 + 3][m] = v.w;
    }
    __syncthreads();
    float acc[4][4];
    {
        float4 bb = ((const float4*)b1)[tx];
        #pragma unroll
        for (int r = 0; r < 4; ++r) { acc[r][0] = bb.x; acc[r][1] = bb.y; acc[r][2] = bb.z; acc[r][3] = bb.w; }
    }
    #pragma unroll 8
    for (int k = 0; k < 64; ++k) {
        float4 a = *(const float4*)&At[k][ty * 4];
        float4 b = *(const float4*)&B1[k][tx * 4];
        mm4x4(acc, a, b);
    }
    __syncthreads();
    for (int i = tid; i < 1024; i += 256) {
        int m = i >> 4, f4 = i & 15, k4 = f4 * 4;
        int node = m0 + m;
        float4 v = make_float4(0.f, 0.f, 0.f, 0.f);
        if (node < n) v = ((const float4*)upd)[node * 16 + f4];
        At[k4 + 0][m] = v.x; At[k4 + 1][m] = v.y; At[k4 + 2][m] = v.z; At[k4 + 3][m] = v.w;
    }
    __syncthreads();
    #pragma unroll 8
    for (int k = 0; k < 64; ++k) {
        float4 a = *(const float4*)&At[k][ty * 4];
        float4 b = *(const float4*)&B1[64 + k][tx * 4];
        mm4x4(acc, a, b);
    }
    __syncthreads();
    #pragma unroll
    for (int r = 0; r < 4; ++r)
        #pragma unroll
        for (int c = 0; c < 4; ++c)
            At[tx * 4 + c][ty * 4 + r] = fmaxf(acc[r][c], 0.f);
    for (int i = tid; i < 1024; i += 256)
        ((float4*)B1)[i] = ((const float4*)w2)[i];
    __syncthreads();
    float acc2[4][4];
    {
        float4 bb = ((const float4*)b2)[tx];
        #pragma unroll
        for (int r = 0; r < 4; ++r) { acc2[r][0] = bb.x; acc2[r][1] = bb.y; acc2[r][2] = bb.z; acc2[r][3] = bb.w; }
    }
    #pragma unroll 8
    for (int k = 0; k < 64; ++k) {
        float4 a = *(const float4*)&At[k][ty * 4];
        float4 b = *(const float4*)&B1[k][tx * 4];
        mm4x4(acc2, a, b);
    }
    float hv[4][4];
    #pragma unroll
    for (int r = 0; r < 4; ++r)
        #pragma unroll
        for (int c = 0; c < 4; ++c)
            hv[r][c] = fmaxf(acc2[r][c], 0.f);
    #pragma unroll
    for (int r = 0; r < 4; ++r) {
        int node = m0 + ty * 4 + r;
        if (node < n)
            ((float4*)h)[node * 16 + tx] = make_float4(hv[r][0], hv[r][1], hv[r][2], hv[r][3]);
    }
    if (write_out) {
        int curg = -1;
        float s0 = 0.f, s1 = 0.f, s2 = 0.f, s3 = 0.f;
        #pragma unroll
        for (int r = 0; r < 4; ++r) {
            int node = m0 + ty * 4 + r;
            if (node < n) {
                int g = n2g[node];
                if (g != curg) {
                    if (curg >= 0) {
                        atomicAdd(&out_graph[curg * 64 + tx * 4 + 0], s0);
                        atomicAdd(&out_graph[curg * 64 + tx * 4 + 1], s1);
                        atomicAdd(&out_graph[curg * 64 + tx * 4 + 2], s2);
                        atomicAdd(&out_graph[curg * 64 + tx * 4 + 3], s3);
                    }
                    curg = g; s0 = hv[r][0]; s1 = hv[r][1]; s2 = hv[r][2]; s3 = hv[r][3];
                } else {
                    s0 += hv[r][0]; s1 += hv[r][1]; s2 += hv[r][2]; s3 += hv[r][3];
                }
            }
        }
        if (curg >= 0) {
            atomicAdd(&out_graph[curg * 64 + tx * 4 + 0], s0);
            atomicAdd(&out_graph[curg * 64 + tx * 4 + 1], s1);
            atomicAdd(&out_graph[curg * 64 + tx * 4 + 2], s2);
            atomicAdd(&out_graph[curg * 64 + tx * 4 + 3], s3);
        }
    }
}

extern "C" void kernel_launch(void* const* d_in, const int* in_sizes, int n_in,
                              void* d_out, int out_size, void* d_ws, size_t ws_size,
                              hipStream_t stream)
{
    const float* x       = (const float*)d_in[0];
    const int*   el      = (const int*)d_in[1];
    const int*   nsc     = (const int*)d_in[2];
    const float* ef      = (const float*)d_in[3];
    const float* ew      = (const float*)d_in[4];
    const int*   n2g     = (const int*)d_in[5];
    const float* lin_w   = (const float*)d_in[7];
    const float* lin_b   = (const float*)d_in[8];
    const float* msg_w1  = (const float*)d_in[9];
    const float* msg_b1  = (const float*)d_in[10];
    const float* msg_w2  = (const float*)d_in[11];
    const float* msg_b2  = (const float*)d_in[12];
    const float* upd_w1  = (const float*)d_in[13];
    const float* upd_b1  = (const float*)d_in[14];
    const float* upd_w2  = (const float*)d_in[15];
    const float* upd_b2  = (const float*)d_in[16];

    float* out_graph = (float*)d_out;              // 128*64
    float* h   = (float*)d_out + 128 * 64;         // node_feature region doubles as h

    // base workspace (R2-proven footprint: 76.8 MB)
    const size_t NNH = (size_t)NN * HID;
    float* p   = (float*)d_ws;
    float* q   = p + NNH;
    float* upd = q + NNH;
    char*  cur = (char*)(upd + NNH);
    const size_t base   = 3 * NNH * sizeof(float);
    const size_t szSd   = (size_t)NE * sizeof(int2);   // 12.8 MB
    const size_t szPerm = (size_t)NE * sizeof(int);    //  6.4 MB
    const size_t szCnt  = (size_t)NN * sizeof(int);    //  0.4 MB
    const size_t szAux  = szPerm + 2 * szCnt + 4096;
    const size_t needB  = base + szAux;                // ~84.2 MB
    const size_t needA  = needB + szSd;                // ~97.0 MB

    // tiered on ws_size (launch-invariant -> graph-capture safe); OOB impossible
    int2* sd_s = nullptr;
    int *perm = nullptr, *counts = nullptr, *offs = nullptr, *blksum = nullptr;
    if (ws_size >= needA) { sd_s = (int2*)cur; cur += szSd; }
    const int do_sort = (ws_size >= needB) ? 1 : 0;
    if (do_sort) {
        perm   = (int*)cur; cur += szPerm;
        counts = (int*)cur; cur += szCnt;
        offs   = (int*)cur; cur += szCnt;
        blksum = (int*)cur;
    } else {
        sd_s = nullptr;
    }

    const int nblk_n  = (NN + 63) / 64;
    const int nblk_e  = (NE + 63) / 64;
    const int nblk_eh = (NE + 255) / 256;
    const int nblk_sc = (NN + 255) / 256;   // 391 <= 512

    hipMemsetAsync(d_out, 0, 128 * 64 * sizeof(float), stream);

    if (do_sort) {
        hipMemsetAsync(counts, 0, szCnt, stream);
        k_hist<<<nblk_eh, 256, 0, stream>>>(el, counts, NE);
        k_scan1<<<nblk_sc, 256, 0, stream>>>(counts, offs, blksum, NN);
        k_scan2<<<1, 512, 0, stream>>>(blksum, nblk_sc);
        k_scan3<<<nblk_sc, 256, 0, stream>>>(offs, blksum, NN);
        k_permute<<<nblk_eh, 256, 0, stream>>>(el, offs, perm, sd_s, NE);
    }

    k_init<<<nblk_n, 256, 0, stream>>>(x, lin_w, lin_b, h, NN);
    for (int l = 0; l < 2; ++l) {
        const float* w1 = msg_w1 + (size_t)l * MSG_IN * HID;
        k_pq<<<nblk_n, 256, 0, stream>>>(h, nsc, w1, msg_b1 + l * HID, p, q, NN);
        hipMemsetAsync(upd, 0, NNH * sizeof(float), stream);
        k_edge<<<nblk_e, 256, 0, stream>>>(sd_s, perm, (const int2*)el, ew, ef, p, q,
                                           w1 + W1E_OFF * HID,
                                           msg_w2 + (size_t)l * HID * HID,
                                           msg_b2 + l * HID, upd, NE);
        k_update<<<nblk_n, 256, 0, stream>>>(h, upd,
                                             upd_w1 + (size_t)l * 2 * HID * HID,
                                             upd_b1 + l * HID,
                                             upd_w2 + (size_t)l * HID * HID,
                                             upd_b2 + l * HID,
                                             NN, (l == 1) ? 1 : 0, out_graph, n2g);
    }
}

// Round 5
// 1735.336 us; speedup vs baseline: 1.8406x; 1.0725x over previous
//
#include <hip/hip_runtime.h>

#define NN 100000
#define NE 1600000
#define HID 64
#define MSG_IN 156   // 2*64 + 2*6 + 16
#define W1E_OFF 140  // rows: [0:64) h_src, [64:128) h_dst, [128:134) sc_src, [134:140) sc_dst, [140:156) ef

__device__ __forceinline__ void mm4x4(float (&acc)[4][4], const float4 a, const float4 b) {
    acc[0][0] = fmaf(a.x, b.x, acc[0][0]);
    acc[0][1] = fmaf(a.x, b.y, acc[0][1]);
    acc[0][2] = fmaf(a.x, b.z, acc[0][2]);
    acc[0][3] = fmaf(a.x, b.w, acc[0][3]);
    acc[1][0] = fmaf(a.y, b.x, acc[1][0]);
    acc[1][1] = fmaf(a.y, b.y, acc[1][1]);
    acc[1][2] = fmaf(a.y, b.z, acc[1][2]);
    acc[1][3] = fmaf(a.y, b.w, acc[1][3]);
    acc[2][0] = fmaf(a.z, b.x, acc[2][0]);
    acc[2][1] = fmaf(a.z, b.y, acc[2][1]);
    acc[2][2] = fmaf(a.z, b.z, acc[2][2]);
    acc[2][3] = fmaf(a.z, b.w, acc[2][3]);
    acc[3][0] = fmaf(a.w, b.x, acc[3][0]);
    acc[3][1] = fmaf(a.w, b.y, acc[3][1]);
    acc[3][2] = fmaf(a.w, b.z, acc[3][2]);
    acc[3][3] = fmaf(a.w, b.w, acc[3][3]);
}

// ---------------- edge preprocessing ----------------

// sw[node] = sum of ew over incoming edges (layer-invariant)
__global__ __launch_bounds__(256) void k_sw(
    const int2* __restrict__ el2, const float* __restrict__ ew,
    float* __restrict__ sw, int n_edges)
{
    int e = blockIdx.x * 256 + threadIdx.x;
    if (e < n_edges) atomicAdd(&sw[el2[e].y], ew[e]);
}

__global__ __launch_bounds__(256) void k_hist(
    const int2* __restrict__ el2, int* __restrict__ counts, int n_edges)
{
    int e = blockIdx.x * 256 + threadIdx.x;
    if (e < n_edges) atomicAdd(&counts[el2[e].y], 1);
}

// in-place-safe block exclusive scan (offs may alias counts)
__global__ __launch_bounds__(256) void k_scan1(
    const int* counts, int* offs, int* __restrict__ blksum, int n)
{
    __shared__ int s[256];
    const int tid = threadIdx.x;
    int i = blockIdx.x * 256 + tid;
    int v = (i < n) ? counts[i] : 0;
    s[tid] = v;
    for (int off = 1; off < 256; off <<= 1) {
        __syncthreads();
        int t = (tid >= off) ? s[tid - off] : 0;
        __syncthreads();
        s[tid] += t;
    }
    __syncthreads();
    if (i < n) offs[i] = s[tid] - v;
    if (tid == 255) blksum[blockIdx.x] = s[255];
}

__global__ __launch_bounds__(512) void k_scan2(int* __restrict__ blksum, int nb)
{
    __shared__ int s[512];
    const int tid = threadIdx.x;
    int v = (tid < nb) ? blksum[tid] : 0;
    s[tid] = v;
    for (int off = 1; off < 512; off <<= 1) {
        __syncthreads();
        int t = (tid >= off) ? s[tid - off] : 0;
        __syncthreads();
        s[tid] += t;
    }
    __syncthreads();
    if (tid < nb) blksum[tid] = s[tid] - v;
}

__global__ __launch_bounds__(256) void k_scan3(
    int* __restrict__ offs, const int* __restrict__ blksum, int n)
{
    int i = blockIdx.x * 256 + threadIdx.x;
    if (i < n) offs[i] += blksum[blockIdx.x];
}

__global__ __launch_bounds__(256) void k_permute(
    const int2* __restrict__ el2, int* __restrict__ cursor,
    int* __restrict__ perm, int n_edges)
{
    int e = blockIdx.x * 256 + threadIdx.x;
    if (e < n_edges) {
        int pos = atomicAdd(&cursor[el2[e].y], 1);
        perm[pos] = e;
    }
}

// C_l = msg_w2_l @ U1b_l ; db_l = msg_b2_l @ U1b_l   (U1b = upd_w1 rows 64..127)
__global__ __launch_bounds__(256) void k_csmall(
    const float* __restrict__ msg_w2, const float* __restrict__ upd_w1,
    const float* __restrict__ msg_b2, float* __restrict__ C2, float* __restrict__ db2)
{
    const int l = blockIdx.x;
    const float* W2  = msg_w2 + (size_t)l * 4096;
    const float* U1b = upd_w1 + (size_t)l * 8192 + 4096;
    const float* b2  = msg_b2 + l * 64;
    float* C  = C2  + (size_t)l * 4096;
    float* db = db2 + l * 64;
    __shared__ __align__(16) float At[64][68];
    __shared__ __align__(16) float B[64][64];
    const int tid = threadIdx.x;
    for (int i = tid; i < 1024; i += 256) {
        ((float4*)B)[i] = ((const float4*)U1b)[i];
        int m = i >> 4, f4 = i & 15, k4 = f4 * 4;
        float4 v = ((const float4*)W2)[m * 16 + f4];
        At[k4 + 0][m] = v.x; At[k4 + 1][m] = v.y; At[k4 + 2][m] = v.z; At[k4 + 3][m] = v.w;
    }
    __syncthreads();
    const int ty = tid >> 4, tx = tid & 15;
    float acc[4][4];
    #pragma unroll
    for (int r = 0; r < 4; ++r) { acc[r][0]=0.f; acc[r][1]=0.f; acc[r][2]=0.f; acc[r][3]=0.f; }
    #pragma unroll 8
    for (int k = 0; k < 64; ++k) {
        float4 a = *(const float4*)&At[k][ty * 4];
        float4 bv = *(const float4*)&B[k][tx * 4];
        mm4x4(acc, a, bv);
    }
    #pragma unroll
    for (int r = 0; r < 4; ++r)
        ((float4*)C)[(ty * 4 + r) * 16 + tx] = make_float4(acc[r][0], acc[r][1], acc[r][2], acc[r][3]);
    if (tid < 64) {
        float sum = 0.f;
        for (int k = 0; k < 64; ++k) sum += b2[k] * B[k][tid];
        db[tid] = sum;
    }
}

// ---------------- dense per-tile GEMM kernels ----------------

// h = x @ lin_w + lin_b
__global__ __launch_bounds__(256) void k_init(
    const float* __restrict__ x, const float* __restrict__ w,
    const float* __restrict__ b, float* __restrict__ h, int n)
{
    __shared__ __align__(16) float At[64][68];
    __shared__ __align__(16) float B[64][64];
    const int tid = threadIdx.x;
    const int m0 = blockIdx.x * 64;
    for (int i = tid; i < 1024; i += 256)
        ((float4*)B)[i] = ((const float4*)w)[i];
    for (int i = tid; i < 1024; i += 256) {
        int m = i >> 4, f4 = i & 15, k4 = f4 * 4;
        int node = m0 + m;
        float4 v = make_float4(0.f, 0.f, 0.f, 0.f);
        if (node < n) v = ((const float4*)x)[node * 16 + f4];
        At[k4 + 0][m] = v.x; At[k4 + 1][m] = v.y; At[k4 + 2][m] = v.z; At[k4 + 3][m] = v.w;
    }
    __syncthreads();
    const int ty = tid >> 4, tx = tid & 15;
    float acc[4][4];
    {
        float4 bb = ((const float4*)b)[tx];
        #pragma unroll
        for (int r = 0; r < 4; ++r) { acc[r][0]=bb.x; acc[r][1]=bb.y; acc[r][2]=bb.z; acc[r][3]=bb.w; }
    }
    #pragma unroll 8
    for (int k = 0; k < 64; ++k) {
        float4 a = *(const float4*)&At[k][ty * 4];
        float4 bv = *(const float4*)&B[k][tx * 4];
        mm4x4(acc, a, bv);
    }
    #pragma unroll
    for (int r = 0; r < 4; ++r) {
        int node = m0 + ty * 4 + r;
        if (node < n)
            ((float4*)h)[node * 16 + tx] = make_float4(acc[r][0], acc[r][1], acc[r][2], acc[r][3]);
    }
}

// p = h@W1a + sc@W1c ; q = h@W1b + sc@W1d + b1
__global__ __launch_bounds__(256) void k_pq(
    const float* __restrict__ h, const int* __restrict__ nsc,
    const float* __restrict__ w1, const float* __restrict__ b1,
    float* __restrict__ p, float* __restrict__ q, int n)
{
    __shared__ __align__(16) float At[64][68];
    __shared__ __align__(16) float Bp[64][64];
    __shared__ __align__(16) float Bq[64][64];
    __shared__ __align__(16) float Sct[6][68];
    __shared__ __align__(16) float Bc[6][64];
    __shared__ __align__(16) float Bd[6][64];
    const int tid = threadIdx.x;
    const int m0 = blockIdx.x * 64;
    for (int i = tid; i < 1024; i += 256) {
        ((float4*)Bp)[i] = ((const float4*)w1)[i];
        ((float4*)Bq)[i] = ((const float4*)(w1 + 64 * 64))[i];
    }
    if (tid < 96) {
        ((float4*)Bc)[tid] = ((const float4*)(w1 + 128 * 64))[tid];
        ((float4*)Bd)[tid] = ((const float4*)(w1 + 134 * 64))[tid];
    }
    for (int i = tid; i < 1024; i += 256) {
        int m = i >> 4, f4 = i & 15, k4 = f4 * 4;
        int node = m0 + m;
        float4 v = make_float4(0.f, 0.f, 0.f, 0.f);
        if (node < n) v = ((const float4*)h)[node * 16 + f4];
        At[k4 + 0][m] = v.x; At[k4 + 1][m] = v.y; At[k4 + 2][m] = v.z; At[k4 + 3][m] = v.w;
    }
    for (int i = tid; i < 384; i += 256) {      // grid-stride: 384 elems, 256 threads
        int m = i & 63, k = i >> 6;
        int node = m0 + m;
        float v = 0.f;
        if (node < n) v = (float)nsc[node * 6 + k];
        Sct[k][m] = v;
    }
    __syncthreads();
    const int ty = tid >> 4, tx = tid & 15;
    float ap[4][4], aq[4][4];
    {
        float4 bb = ((const float4*)b1)[tx];
        #pragma unroll
        for (int r = 0; r < 4; ++r) {
            ap[r][0]=0.f; ap[r][1]=0.f; ap[r][2]=0.f; ap[r][3]=0.f;
            aq[r][0]=bb.x; aq[r][1]=bb.y; aq[r][2]=bb.z; aq[r][3]=bb.w;
        }
    }
    #pragma unroll 8
    for (int k = 0; k < 64; ++k) {
        float4 a  = *(const float4*)&At[k][ty * 4];
        float4 bp = *(const float4*)&Bp[k][tx * 4];
        float4 bq = *(const float4*)&Bq[k][tx * 4];
        mm4x4(ap, a, bp);
        mm4x4(aq, a, bq);
    }
    #pragma unroll
    for (int k = 0; k < 6; ++k) {
        float4 a  = *(const float4*)&Sct[k][ty * 4];
        float4 bc = *(const float4*)&Bc[k][tx * 4];
        float4 bd = *(const float4*)&Bd[k][tx * 4];
        mm4x4(ap, a, bc);
        mm4x4(aq, a, bd);
    }
    #pragma unroll
    for (int r = 0; r < 4; ++r) {
        int node = m0 + ty * 4 + r;
        if (node < n) {
            ((float4*)p)[node * 16 + tx] = make_float4(ap[r][0], ap[r][1], ap[r][2], ap[r][3]);
            ((float4*)q)[node * 16 + tx] = make_float4(aq[r][0], aq[r][1], aq[r][2], aq[r][3]);
        }
    }
}

// hidden-space edge kernel (W2 hoisted out): per 64-edge dst-sorted tile,
// hid = relu(p[src]+q[dst]+ef@W1e); S[dst] += ew*hid  (run-length-reduced atomics)
// ~9.5 KB LDS -> 8 blocks/CU occupancy; XCD-contiguous tile swizzle for S/q L2 locality
__global__ __launch_bounds__(256) void k_edge2(
    const int* __restrict__ perm, const int2* __restrict__ el2,
    const float* __restrict__ ew, const float* __restrict__ ef,
    const float* __restrict__ p, const float* __restrict__ q,
    const float* __restrict__ w1e, float* __restrict__ S, int n_edges)
{
    __shared__ __align__(16) float Et[16][68];
    __shared__ __align__(16) float W1e[16][64];
    __shared__ int Ssrc[64];
    __shared__ int Sdst[64];
    __shared__ float Sew[64];
    const int tid = threadIdx.x;
    const int b = blockIdx.x, nb = gridDim.x;
    // round-robin b->XCD assumed: give each XCD a contiguous tile range
    const int tile = ((nb & 7) == 0) ? ((b & 7) * (nb >> 3) + (b >> 3)) : b;
    const int e0 = tile * 64;
    if (tid < 64) {
        int e = e0 + tid;
        int s = 0, d = 0; float w = 0.f;
        if (e < n_edges) {
            int pe = perm ? perm[e] : e;
            int2 sd = el2[pe];
            s = sd.x; d = sd.y; w = ew[pe];
        }
        Ssrc[tid] = s; Sdst[tid] = d; Sew[tid] = w;
    }
    ((float4*)W1e)[tid] = ((const float4*)w1e)[tid];
    {
        int e = tid >> 2, f4 = tid & 3, k4 = f4 * 4;
        int ge = e0 + e;
        float4 v = make_float4(0.f, 0.f, 0.f, 0.f);
        if (ge < n_edges) {
            int pe = perm ? perm[ge] : ge;     // 4 lanes share one perm read
            v = ((const float4*)ef)[(size_t)pe * 4 + f4];
        }
        Et[k4 + 0][e] = v.x; Et[k4 + 1][e] = v.y; Et[k4 + 2][e] = v.z; Et[k4 + 3][e] = v.w;
    }
    __syncthreads();
    const int ty = tid >> 4, tx = tid & 15;
    float acc[4][4];
    #pragma unroll
    for (int r = 0; r < 4; ++r) {
        int s = Ssrc[ty * 4 + r], d = Sdst[ty * 4 + r];
        float4 pv = ((const float4*)p)[(size_t)s * 16 + tx];
        float4 qv = ((const float4*)q)[(size_t)d * 16 + tx];   // sorted: cache-resident runs
        acc[r][0] = pv.x + qv.x; acc[r][1] = pv.y + qv.y;
        acc[r][2] = pv.z + qv.z; acc[r][3] = pv.w + qv.w;
    }
    #pragma unroll
    for (int k = 0; k < 16; ++k) {
        float4 a = *(const float4*)&Et[k][ty * 4];
        float4 bv = *(const float4*)&W1e[k][tx * 4];
        mm4x4(acc, a, bv);
    }
    // run-length reduction of w*relu(hid) over 4 consecutive sorted edges
    {
        int curd = -1;
        float s0 = 0.f, s1 = 0.f, s2 = 0.f, s3 = 0.f;
        #pragma unroll
        for (int r = 0; r < 4; ++r) {
            int le = ty * 4 + r;
            int ge = e0 + le;
            if (ge < n_edges) {
                int d = Sdst[le];
                float w = Sew[le];
                float v0 = fmaxf(acc[r][0], 0.f) * w;
                float v1 = fmaxf(acc[r][1], 0.f) * w;
                float v2 = fmaxf(acc[r][2], 0.f) * w;
                float v3 = fmaxf(acc[r][3], 0.f) * w;
                if (d != curd) {
                    if (curd >= 0) {
                        atomicAdd(&S[(size_t)curd * 64 + tx * 4 + 0], s0);
                        atomicAdd(&S[(size_t)curd * 64 + tx * 4 + 1], s1);
                        atomicAdd(&S[(size_t)curd * 64 + tx * 4 + 2], s2);
                        atomicAdd(&S[(size_t)curd * 64 + tx * 4 + 3], s3);
                    }
                    curd = d; s0 = v0; s1 = v1; s2 = v2; s3 = v3;
                } else {
                    s0 += v0; s1 += v1; s2 += v2; s3 += v3;
                }
            }
        }
        if (curd >= 0) {
            atomicAdd(&S[(size_t)curd * 64 + tx * 4 + 0], s0);
            atomicAdd(&S[(size_t)curd * 64 + tx * 4 + 1], s1);
            atomicAdd(&S[(size_t)curd * 64 + tx * 4 + 2], s2);
            atomicAdd(&S[(size_t)curd * 64 + tx * 4 + 3], s3);
        }
    }
}

// h = relu(relu(h@U1a + S@C + sw*db + ub1)@uw2 + ub2); optional fused graph segsum
__global__ __launch_bounds__(256) void k_update(
    float* __restrict__ h, const float* __restrict__ S,
    const float* __restrict__ w1, const float* __restrict__ C,
    const float* __restrict__ b1, const float* __restrict__ w2,
    const float* __restrict__ b2, const float* __restrict__ db,
    const float* __restrict__ sw,
    int n, int write_out, float* __restrict__ out_graph,
    const int* __restrict__ n2g)
{
    __shared__ __align__(16) float At[64][68];
    __shared__ __align__(16) float B1[128][64];
    __shared__ float Db[64];
    const int tid = threadIdx.x;
    const int m0 = blockIdx.x * 64;
    const int ty = tid >> 4, tx = tid & 15;
    if (tid < 64) Db[tid] = db[tid];
    for (int i = tid; i < 2048; i += 256)
        ((float4*)B1)[i] = (i < 1024) ? ((const float4*)w1)[i] : ((const float4*)C)[i - 1024];
    for (int i = tid; i < 1024; i += 256) {
        int m = i >> 4, f4 = i & 15, k4 = f4 * 4;
        int node = m0 + m;
        float4 v = make_float4(0.f, 0.f, 0.f, 0.f);
        if (node < n) v = ((const float4*)h)[node * 16 + f4];
        At[k4 + 0][m] = v.x; At[k4 + 1][m] = v.y; At[k4 + 2][m] = v.z; At[k4 + 3][m] = v.w;
    }
    __syncthreads();
    float acc[4][4];
    {
        float4 bb = ((const float4*)b1)[tx];
        #pragma unroll
        for (int r = 0; r < 4; ++r) { acc[r][0]=bb.x; acc[r][1]=bb.y; acc[r][2]=bb.z; acc[r][3]=bb.w; }
    }
    #pragma unroll 8
    for (int k = 0; k < 64; ++k) {
        float4 a = *(const float4*)&At[k][ty * 4];
        float4 bv = *(const float4*)&B1[k][tx * 4];
        mm4x4(acc, a, bv);
    }
    __syncthreads();
    for (int i = tid; i < 1024; i += 256) {
        int m = i >> 4, f4 = i & 15, k4 = f4 * 4;
        int node = m0 + m;
        float4 v = make_float4(0.f, 0.f, 0.f, 0.f);
        if (node < n) v = ((const float4*)S)[node * 16 + f4];
        At[k4 + 0][m] = v.x; At[k4 + 1][m] = v.y; At[k4 + 2][m] = v.z; At[k4 + 3][m] = v.w;
    }
    __syncthreads();
    #pragma unroll 8
    for (int k = 0; k < 64; ++k) {
        float4 a = *(const float4*)&At[k][ty * 4];
        float4 bv = *(const float4*)&B1[64 + k][tx * 4];
        mm4x4(acc, a, bv);
    }
    // + sw[node] * db[col]   (hoisted b2 contribution through U1b)
    #pragma unroll
    for (int r = 0; r < 4; ++r) {
        int node = m0 + ty * 4 + r;
        float swv = (node < n) ? sw[node] : 0.f;
        #pragma unroll
        for (int c = 0; c < 4; ++c)
            acc[r][c] = fmaf(swv, Db[tx * 4 + c], acc[r][c]);
    }
    __syncthreads();
    #pragma unroll
    for (int r = 0; r < 4; ++r)
        #pragma unroll
        for (int c = 0; c < 4; ++c)
            At[tx * 4 + c][ty * 4 + r] = fmaxf(acc[r][c], 0.f);
    for (int i = tid; i < 1024; i += 256)
        ((float4*)B1)[i] = ((const float4*)w2)[i];
    __syncthreads();
    float acc2[4][4];
    {
        float4 bb = ((const float4*)b2)[tx];
        #pragma unroll
        for (int r = 0; r < 4; ++r) { acc2[r][0]=bb.x; acc2[r][1]=bb.y; acc2[r][2]=bb.z; acc2[r][3]=bb.w; }
    }
    #pragma unroll 8
    for (int k = 0; k < 64; ++k) {
        float4 a = *(const float4*)&At[k][ty * 4];
        float4 bv = *(const float4*)&B1[k][tx * 4];
        mm4x4(acc2, a, bv);
    }
    float hv[4][4];
    #pragma unroll
    for (int r = 0; r < 4; ++r)
        #pragma unroll
        for (int c = 0; c < 4; ++c)
            hv[r][c] = fmaxf(acc2[r][c], 0.f);
    #pragma unroll
    for (int r = 0; r < 4; ++r) {
        int node = m0 + ty * 4 + r;
        if (node < n)
            ((float4*)h)[node * 16 + tx] = make_float4(hv[r][0], hv[r][1], hv[r][2], hv[r][3]);
    }
    if (write_out) {
        int curg = -1;
        float s0 = 0.f, s1 = 0.f, s2 = 0.f, s3 = 0.f;
        #pragma unroll
        for (int r = 0; r < 4; ++r) {
            int node = m0 + ty * 4 + r;
            if (node < n) {
                int g = n2g[node];
                if (g != curg) {
                    if (curg >= 0) {
                        atomicAdd(&out_graph[curg * 64 + tx * 4 + 0], s0);
                        atomicAdd(&out_graph[curg * 64 + tx * 4 + 1], s1);
                        atomicAdd(&out_graph[curg * 64 + tx * 4 + 2], s2);
                        atomicAdd(&out_graph[curg * 64 + tx * 4 + 3], s3);
                    }
                    curg = g; s0 = hv[r][0]; s1 = hv[r][1]; s2 = hv[r][2]; s3 = hv[r][3];
                } else {
                    s0 += hv[r][0]; s1 += hv[r][1]; s2 += hv[r][2]; s3 += hv[r][3];
                }
            }
        }
        if (curg >= 0) {
            atomicAdd(&out_graph[curg * 64 + tx * 4 + 0], s0);
            atomicAdd(&out_graph[curg * 64 + tx * 4 + 1], s1);
            atomicAdd(&out_graph[curg * 64 + tx * 4 + 2], s2);
            atomicAdd(&out_graph[curg * 64 + tx * 4 + 3], s3);
        }
    }
}

extern "C" void kernel_launch(void* const* d_in, const int* in_sizes, int n_in,
                              void* d_out, int out_size, void* d_ws, size_t ws_size,
                              hipStream_t stream)
{
    const float* x       = (const float*)d_in[0];
    const int2*  el2     = (const int2*)d_in[1];
    const int*   nsc     = (const int*)d_in[2];
    const float* ef      = (const float*)d_in[3];
    const float* ew      = (const float*)d_in[4];
    const int*   n2g     = (const int*)d_in[5];
    const float* lin_w   = (const float*)d_in[7];
    const float* lin_b   = (const float*)d_in[8];
    const float* msg_w1  = (const float*)d_in[9];
    const float* msg_b1  = (const float*)d_in[10];
    const float* msg_w2  = (const float*)d_in[11];
    const float* upd_w1  = (const float*)d_in[13];
    const float* upd_b1  = (const float*)d_in[14];
    const float* upd_w2  = (const float*)d_in[15];
    const float* upd_b2  = (const float*)d_in[16];
    const float* msg_b2  = (const float*)d_in[12];

    float* out_graph = (float*)d_out;              // 128*64
    float* h   = (float*)d_out + 128 * 64;         // node_feature region doubles as h

    // workspace layout; proven ws >= 84.2 MB (R4 sort tier engaged)
    const size_t NNH = (size_t)NN * HID;
    float* p  = (float*)d_ws;                     // 25.6 MB
    float* q  = p + NNH;                          // 25.6 MB
    float* S  = q + NNH;                          // 25.6 MB
    char*  cur = (char*)(S + NNH);
    const size_t base   = 3 * NNH * sizeof(float);         // 76.8 MB
    const size_t szPerm = (size_t)NE * sizeof(int);        //  6.4 MB
    const size_t szCnt  = (size_t)NN * sizeof(int);        //  0.4 MB
    const size_t szSw   = (size_t)NN * sizeof(float);      //  0.4 MB
    const size_t szBlk  = 4096;
    const size_t szC    = 2 * 64 * 64 * sizeof(float);     // 32 KB
    const size_t szDb   = 2 * 64 * sizeof(float);
    const size_t need_sort = base + szPerm + szCnt + szBlk + szSw + szC + szDb; // ~84.04 MB

    int *perm = nullptr, *counts = nullptr, *blksum = nullptr;
    float *sw, *C2, *db2;
    const int do_sort = (ws_size >= need_sort) ? 1 : 0;
    if (do_sort) {
        perm   = (int*)cur;        cur += szPerm;
        counts = (int*)cur;        cur += szCnt;
        blksum = (int*)cur;        cur += szBlk;
    }
    sw  = (float*)cur;             cur += szSw;
    C2  = (float*)cur;             cur += szC;
    db2 = (float*)cur;

    const int nblk_n  = (NN + 63) / 64;
    const int nblk_e  = (NE + 63) / 64;      // 25000 = 8 * 3125 -> swizzle active
    const int nblk_eh = (NE + 255) / 256;
    const int nblk_sc = (NN + 255) / 256;    // 391 <= 512

    hipMemsetAsync(d_out, 0, 128 * 64 * sizeof(float), stream);
    hipMemsetAsync(sw, 0, szSw, stream);
    k_sw<<<nblk_eh, 256, 0, stream>>>(el2, ew, sw, NE);

    if (do_sort) {
        hipMemsetAsync(counts, 0, szCnt, stream);
        k_hist<<<nblk_eh, 256, 0, stream>>>(el2, counts, NE);
        k_scan1<<<nblk_sc, 256, 0, stream>>>(counts, counts, blksum, NN);  // in-place
        k_scan2<<<1, 512, 0, stream>>>(blksum, nblk_sc);
        k_scan3<<<nblk_sc, 256, 0, stream>>>(counts, blksum, NN);
        k_permute<<<nblk_eh, 256, 0, stream>>>(el2, counts, perm, NE);
    }
    k_csmall<<<2, 256, 0, stream>>>(msg_w2, upd_w1, msg_b2, C2, db2);

    k_init<<<nblk_n, 256, 0, stream>>>(x, lin_w, lin_b, h, NN);
    for (int l = 0; l < 2; ++l) {
        const float* w1 = msg_w1 + (size_t)l * MSG_IN * HID;
        k_pq<<<nblk_n, 256, 0, stream>>>(h, nsc, w1, msg_b1 + l * HID, p, q, NN);
        hipMemsetAsync(S, 0, NNH * sizeof(float), stream);
        k_edge2<<<nblk_e, 256, 0, stream>>>(perm, el2, ew, ef, p, q,
                                            w1 + W1E_OFF * HID, S, NE);
        k_update<<<nblk_n, 256, 0, stream>>>(h, S,
                                             upd_w1 + (size_t)l * 2 * HID * HID,
                                             C2 + (size_t)l * 4096,
                                             upd_b1 + l * HID,
                                             upd_w2 + (size_t)l * HID * HID,
                                             upd_b2 + l * HID,
                                             db2 + l * 64, sw,
                                             NN, (l == 1) ? 1 : 0, out_graph, n2g);
    }
}